// Round 4
// baseline (290.893 us; speedup 1.0000x reference)
//
#include <hip/hip_runtime.h>

#define IMG    512
#define TW     32
#define TH     48
#define R      5
#define KW     11
#define HB_H   (TH + 2*R)            // 58
#define W4     33                    // hb4 padded row stride (float4 cells)
#define W1     36                    // hb1 padded row stride (floats)
#define GX     (IMG / TW)            // 16
#define GY     ((IMG + TH - 1) / TH) // 11 (last tile rows 480..527, 32 valid)
#define NBATCH 32
#define NBLOCKS (GX * GY * NBATCH)   // 5632
#define C1f 0.0001f
#define C2f 0.0009f

// LDS = 58*33*16 + 58*36*4 + 16 = 38,992 B -> 4 blocks/CU (16 waves, 50%)
__global__ __launch_bounds__(256, 4) void ssim_fused_kernel(
    const float* __restrict__ x, const float* __restrict__ y,
    float* __restrict__ out, float* __restrict__ ws)
{
    __shared__ float4 hb4[HB_H][W4];  // (mu_x, mu_y, E[xx], E[yy]) horiz-filtered
    __shared__ float  hb1[HB_H][W1];  // E[xy] horiz-filtered
    __shared__ float  red[4];

    // normalized 1D Gaussian, sigma=1.5, k=11 (literals; ~1e-7 vs expf path)
    const float W[KW] = {
        0.00102838f, 0.00759874f, 0.03600077f, 0.10936075f, 0.21300553f,
        0.26601172f,
        0.21300553f, 0.10936075f, 0.03600077f, 0.00759874f, 0.00102838f};

    const int tc = blockIdx.x, tr = blockIdx.y, b = blockIdx.z;
    const int tid = threadIdx.x;
    const size_t imgBase = (size_t)b * (IMG * IMG);
    const int gr0 = tr * TH - R;
    const bool colEdge = (tc == 0) || (tc == GX - 1);

    // ========== horizontal pass: 4-px items, strided (round-2 structure) ======
    for (int it = tid; it < HB_H * 8; it += 256) {
        const int rr = it >> 3;          // staged row 0..57
        const int g  = it & 7;           // 4-px group in row
        const int gr = gr0 + rr;
        const bool rowok = (unsigned)gr < (unsigned)IMG;
        if (!rowok) {
            const float4 z = make_float4(0.f, 0.f, 0.f, 0.f);
#pragma unroll
            for (int k = 0; k < 4; ++k) {
                hb4[rr][4*g + k] = z;
                hb1[rr][4*g + k] = 0.f;
            }
            continue;
        }
        const float4* rx = (const float4*)(x + imgBase + (size_t)gr * IMG);
        const float4* ry = (const float4*)(y + imgBase + (size_t)gr * IMG);
        const int c4 = tc * 8 + g - 2;   // first float4; taps use floats f[3..16]
        float fx[20], fy[20];
        if (colEdge) {
#pragma unroll
            for (int i = 0; i < 5; ++i) {
                int q = c4 + i;
                int qc = min(max(q, 0), IMG / 4 - 1);
                float4 vx = rx[qc], vy = ry[qc];
                float m = (q == qc) ? 1.f : 0.f;
                fx[4*i+0]=vx.x*m; fx[4*i+1]=vx.y*m; fx[4*i+2]=vx.z*m; fx[4*i+3]=vx.w*m;
                fy[4*i+0]=vy.x*m; fy[4*i+1]=vy.y*m; fy[4*i+2]=vy.z*m; fy[4*i+3]=vy.w*m;
            }
        } else {
#pragma unroll
            for (int i = 0; i < 5; ++i) {
                float4 vx = rx[c4 + i], vy = ry[c4 + i];
                fx[4*i+0]=vx.x; fx[4*i+1]=vx.y; fx[4*i+2]=vx.z; fx[4*i+3]=vx.w;
                fy[4*i+0]=vy.x; fy[4*i+1]=vy.y; fy[4*i+2]=vy.z; fy[4*i+3]=vy.w;
            }
        }
        float xx[14], yy[14], xy[14];
#pragma unroll
        for (int t = 0; t < 14; ++t) {
            float px = fx[3 + t], py = fy[3 + t];
            xx[t] = px * px; yy[t] = py * py; xy[t] = px * py;
        }
#pragma unroll
        for (int k = 0; k < 4; ++k) {
            float a0 = 0.f, a1 = 0.f, a2 = 0.f, a3 = 0.f, a4 = 0.f;
#pragma unroll
            for (int t = 0; t < KW; ++t) {
                const float wt = W[t];
                const int j = k + t;
                a0 += wt * fx[3 + j];
                a1 += wt * fy[3 + j];
                a2 += wt * xx[j];
                a3 += wt * yy[j];
                a4 += wt * xy[j];
            }
            hb4[rr][4*g + k] = make_float4(a0, a1, a2, a3);
            hb1[rr][4*g + k] = a4;
        }
    }
    __syncthreads();

    // ========== vertical pass + SSIM epilogue: 6 rows/thread ==========
    const int tx = tid & 31;
    const int ty = tid >> 5;
    const int r0 = ty * 6;

    float a0[6], a1[6], a2[6], a3[6], a4[6];
#pragma unroll
    for (int k = 0; k < 6; ++k) { a0[k]=0.f; a1[k]=0.f; a2[k]=0.f; a3[k]=0.f; a4[k]=0.f; }

#pragma unroll
    for (int t = 0; t < 16; ++t) {       // tap rows r0 .. r0+15
        float4 v4 = hb4[r0 + t][tx];
        float  v1 = hb1[r0 + t][tx];
#pragma unroll
        for (int k = 0; k < 6; ++k) {
            const int u = t - k;
            if (u >= 0 && u < KW) {      // constant-folds under full unroll
                const float wt = W[u];
                a0[k] += wt * v4.x;
                a1[k] += wt * v4.y;
                a2[k] += wt * v4.z;
                a3[k] += wt * v4.w;
                a4[k] += wt * v1;
            }
        }
    }

    float lsum = 0.f;
    const int grOut = tr * TH + r0;
#pragma unroll
    for (int k = 0; k < 6; ++k) {
        float mux = a0[k], muy = a1[k];
        float sxx = a2[k] - mux * mux;
        float syy = a3[k] - muy * muy;
        float sxy = a4[k] - mux * muy;
        float num = (2.f * mux * muy + C1f) * (2.f * sxy + C2f);
        float den = (mux * mux + muy * muy + C1f) * (sxx + syy + C2f);
        float ssim = num / (den + 1e-12f);
        ssim = fminf(fmaxf(ssim, -1.f + 1e-6f), 1.f - 1e-6f);
        lsum += (grOut + k < IMG) ? ssim : 0.f;
    }

    // ========== block reduction + fused finalize ==========
#pragma unroll
    for (int off = 32; off > 0; off >>= 1)
        lsum += __shfl_down(lsum, off, 64);
    if ((tid & 63) == 0) red[tid >> 6] = lsum;
    __syncthreads();
    if (tid == 0) {
        float s = red[0] + red[1] + red[2] + red[3];
        atomicAdd(&ws[0], s);                       // device-scope by default
        __threadfence();
        unsigned old = atomicAdd((unsigned*)&ws[1], 1u);
        if (old == (unsigned)(NBLOCKS - 1)) {       // last block finalizes
            __threadfence();
            float tot = atomicAdd(&ws[0], 0.0f);    // coherent read
            out[0] = 1.0f - tot * (1.0f / (32.0f * 512.0f * 512.0f));
        }
    }
}

extern "C" void kernel_launch(void* const* d_in, const int* in_sizes, int n_in,
                              void* d_out, int out_size, void* d_ws, size_t ws_size,
                              hipStream_t stream) {
    const float* x = (const float*)d_in[0];
    const float* y = (const float*)d_in[1];
    float* out = (float*)d_out;
    float* ws  = (float*)d_ws;   // ws[0]=sum accumulator, ws[1]=done counter

    hipMemsetAsync(d_ws, 0, 2 * sizeof(float), stream);  // graph-capture legal
    dim3 grid(GX, GY, NBATCH);
    ssim_fused_kernel<<<grid, 256, 0, stream>>>(x, y, out, ws);
}